// Round 13
// baseline (136.975 us; speedup 1.0000x reference)
//
#include <hip/hip_runtime.h>

// R30 = R29 (best, 136.3us) with the GNN WEIGHT-LO term DROPPED: consume is
// now pure bf16xbf16 (2 MFMAs/tile, was 4; 32 MFMA/thread @K=128, was 64);
// wload halves; -8 VGPR. The wl correction (rel 2^-9) is meaningless under
// the already-bf16 aggregate (R27) and bf16 h (R21). absmax has stepped in
// powers of 2 as rounding classes were added (2^-13 -> 2^-11 -> 2^-10);
// predicted now 2^-9 = 1.95e-3 vs threshold 4.375e-3 (2.2x margin).
// Prep keeps exact obs hi/lo (untouched this round -- one lever at a time).
// Ledger: traffic cuts pay (R21 -10), contention removal pays (R26 -3),
// issue cuts pay (R27 -3.4, R28 -2.7, R29 -3.5); falsified: gnn-fusion
// (R18), prep phases (R20), depth>2 (R22), WG ramp (R23), store coalescing
// (R24), fence fusion (R25: agent-release -> buffer_wbl2 storm; NEVER fence
// in wide kernels). Fill ~44us = harness memset of 256MB ws, not ours.
//
// Intermediates bf16 FEATURE-MAJOR h[b][f][n], n = 64x64 grid.
// GNN layer exact rewrite: h' = relu( agg(h) @ W + rowsum*b ).
// gnn: bf16 agg x bf16 weight, 1 MFMA per (tile,ftl).  prep L1: 3-MFMA
// hi/lo obs, prep L2: bf16 act, 2 MFMAs (weight hi+lo).
//
// MFMA 16x16x32 bf16 layouts (verified m89/m120):
//   A (MxK): m = lane&15, k = quad*8 + j    B (KxN): n = lane&15, k = quad*8 + j
//   C/D: col(N) = lane&15, row(M) = quad*4 + reg

typedef __attribute__((ext_vector_type(8))) short bf16x8;
typedef __attribute__((ext_vector_type(4))) float f32x4;
#define MFMA(a, b, c) __builtin_amdgcn_mfma_f32_16x16x32_bf16(a, b, c, 0, 0, 0)

// barrier with LDS visibility but WITHOUT draining global loads:
// s_waitcnt imm 0xC07F = vmcnt(63) expcnt(7) lgkmcnt(0)
__device__ inline void block_sync_lgkm() {
    asm volatile("" ::: "memory");
    __builtin_amdgcn_s_waitcnt(0xC07F);
    __builtin_amdgcn_s_barrier();
    asm volatile("" ::: "memory");
}

__device__ inline ushort bf16h(float x) {
    unsigned u = __float_as_uint(x);
    return (ushort)((u + 0x7fffu + ((u >> 16) & 1u)) >> 16);
}
__device__ inline void split_bf16(float x, ushort& hi, ushort& lo) {
    hi = bf16h(x);
    lo = bf16h(x - __uint_as_float(((unsigned)hi) << 16));
}
// packed (hi16 << 16) | lo16 ; hi = RNE, lo = truncation
__device__ inline unsigned pack_split(float x) {
    unsigned u = __float_as_uint(x);
    unsigned hi = (u + 0x7fffu + ((u >> 16) & 1u)) >> 16;
    float r = x - __uint_as_float(hi << 16);
    return (hi << 16) | (__float_as_uint(r) >> 16);
}
// bf16 pair in a u32: even node = low ushort, odd node = high ushort
__device__ inline float bflo(unsigned w) { return __uint_as_float(w << 16); }
__device__ inline float bfhi(unsigned w) { return __uint_as_float(w & 0xFFFF0000u); }
// 8 packed u32 (stride 65) -> hi/lo bf16x8 fragments (prep L1 path)
__device__ inline void frag_packed(const unsigned* bp, bf16x8& bh, bf16x8& bl) {
    unsigned p[8];
#pragma unroll
    for (int j = 0; j < 8; j++) p[j] = bp[j * 65];
    union { bf16x8 v; unsigned d[4]; } H, L;
#pragma unroll
    for (int j = 0; j < 4; j++) {
        const unsigned e = p[2 * j], o = p[2 * j + 1];
        H.d[j] = (o & 0xFFFF0000u) | (e >> 16);
        L.d[j] = (o << 16) | (e & 0xFFFFu);
    }
    bh = H.v; bl = L.v;
}
// 4 k-paired u32 (stride 65) -> bf16x8 fragment, zero repack (gnn + prep L2)
__device__ inline void frag_kp(const unsigned* bp, bf16x8& bh) {
    union { bf16x8 v; unsigned d[4]; } H;
    H.d[0] = bp[0]; H.d[1] = bp[65]; H.d[2] = bp[130]; H.d[3] = bp[195];
    bh = H.v;
}

// ---- launch 1: embed (1024 blocks); g-weight prep folded into first 20 ----
// g-frag unit (kc,t) = 2 planes x 512 ushorts; per layer unit idx = kc*8 + t.
// wfb ushort offsets: g1@12288 (16 units), g2@28672 (32), g3@61440 (32).
__global__ __launch_bounds__(256, 4) void prep_embed_kernel(
    const float* __restrict__ obs,
    const float* __restrict__ e1w, const float* __restrict__ e1b,
    const float* __restrict__ e2w, const float* __restrict__ e2b,
    const float* __restrict__ g1w, const float* __restrict__ g2w,
    const float* __restrict__ g3w, ushort* __restrict__ wf,
    ushort* __restrict__ h0)
{
    const int blk = blockIdx.x, tid = threadIdx.x;

    // ---- aux: g-weight prep (blk<20, 4 units/block).
    // Outputs consumed only by LATER launches -> no intra-kernel ordering.
    if (blk < 20) {
        const int u = blk * 4 + (tid >> 6);
        const int l = tid & 63;
        const float* src; int K, kc, t; ushort* dst;
        if (u < 16)      { src = g1w; K = 64;  kc = u >> 3;        t = u & 7; dst = wf + 12288; }
        else if (u < 48) { src = g2w; K = 128; kc = (u - 16) >> 3; t = (u - 16) & 7; dst = wf + 28672; }
        else             { src = g3w; K = 128; kc = (u - 48) >> 3; t = (u - 48) & 7; dst = wf + 61440; }
        ushort* uh = dst + ((kc * 8 + t) * 2 + 0) * 512 + l * 8;
        ushort* ul = dst + ((kc * 8 + t) * 2 + 1) * 512 + l * 8;
        const int fw = t * 16 + (l & 15);
        const int kb = kc * 32 + ((l >> 4) << 3);
#pragma unroll
        for (int j = 0; j < 8; j++) {
            const int k = kb + j;
            const float wv = (k < K) ? src[k * 128 + fw] : 0.f;
            ushort hi, lo; split_bf16(wv, hi, lo);
            uh[j] = hi; ul[j] = lo;
        }
    }

    // ---- embed: block = (b, row) = 64 nodes, fused 2-layer MLP via MFMA ----
    __shared__ unsigned lds[4160];         // Xs = lds[0..2080), Hs = lds+2080
                                           // Hs: 32 kpair-rows x 65 (k-paired)
    // XCD remap ALIGNED with gnn readers: h0 rows land on the XCD that reads them
    const int ebid = ((blk & 7) << 7) | (blk >> 3);
    const int b = ebid >> 6, row = ebid & 63;
    const int lane = tid & 63, w = tid >> 6, quad = lane >> 4, nl = lane & 15;
    const int cp = tid >> 4, nq = tid & 15;

    // obs load issued early (used in phase X)
    const float4 x4 = *(const float4*)(obs + ((size_t)(b * 16 + cp) << 12) + row * 64 + nq * 4);

    // weight fragments DIRECT from global (e1w 4KB + e2w 16KB, L1-resident
    // after the first block on each CU; 64B-per-quad coalesced segments)
    float e1f[8], e2f[16];
    {
        const int f = 16 * w + nl;
#pragma unroll
        for (int j = 0; j < 8; j++) {
            const int k = quad * 8 + j;
            e1f[j] = (k < 16) ? e1w[k * 64 + f] : 0.f;
        }
#pragma unroll
        for (int kc = 0; kc < 2; kc++)
#pragma unroll
            for (int j = 0; j < 8; j++)
                e2f[kc * 8 + j] = e2w[(kc * 32 + quad * 8 + j) * 64 + f];
    }

    // phase X: stage obs packed (B-operand planes, k>=16 zeroed)
    unsigned* Xs = lds;
    unsigned* Hs = lds + 2080;
    {
        unsigned* xp = Xs + cp * 65 + nq * 4;
        xp[0] = pack_split(x4.x); xp[1] = pack_split(x4.y);
        xp[2] = pack_split(x4.z); xp[3] = pack_split(x4.w);
        unsigned* zp = Xs + (16 + cp) * 65 + nq * 4;
        zp[0] = 0u; zp[1] = 0u; zp[2] = 0u; zp[3] = 0u;
    }

    // build this wave's weight fragments in registers (A-operand, M=feats);
    // VALU-only, overlaps the weight-load latency before the barrier
    bf16x8 e1h, e1l, e2h[2], e2l[2];
#pragma unroll
    for (int j = 0; j < 8; j++) {
        ushort hi, lo; split_bf16(e1f[j], hi, lo);
        e1h[j] = (short)hi; e1l[j] = (short)lo;
    }
#pragma unroll
    for (int kc = 0; kc < 2; kc++)
#pragma unroll
        for (int j = 0; j < 8; j++) {
            ushort hi, lo; split_bf16(e2f[kc * 8 + j], hi, lo);
            e2h[kc][j] = (short)hi; e2l[kc][j] = (short)lo;
        }
    __syncthreads();

    // layer 1: wave w -> mid-feats 16w..16w+15 (exact hi/lo obs, 3 MFMA);
    // activations stored bf16, K-PAIRED: dword = {fm even (lo), fm odd (hi)}
#pragma unroll
    for (int nt = 0; nt < 4; nt++) {
        const unsigned* bp = Xs + (quad * 8) * 65 + nt * 16 + nl;
        bf16x8 bh, bl; frag_packed(bp, bh, bl);
        f32x4 c = {0.f, 0.f, 0.f, 0.f};
        c = MFMA(e1h, bh, c); c = MFMA(e1h, bl, c); c = MFMA(e1l, bh, c);
        const int fmb = 16 * w + quad * 4;
        const unsigned d0 =
            (unsigned)bf16h(fmaxf(c[0] + e1b[fmb + 0], 0.f)) |
            ((unsigned)bf16h(fmaxf(c[1] + e1b[fmb + 1], 0.f)) << 16);
        const unsigned d1 =
            (unsigned)bf16h(fmaxf(c[2] + e1b[fmb + 2], 0.f)) |
            ((unsigned)bf16h(fmaxf(c[3] + e1b[fmb + 3], 0.f)) << 16);
        const int hr = 8 * w + quad * 2;
        Hs[hr * 65 + nt * 16 + nl] = d0;
        Hs[(hr + 1) * 65 + nt * 16 + nl] = d1;
    }
    __syncthreads();

    // layer 2: K=64 (2 kc), bf16 activations k-paired, 4 reads + 2 MFMAs/tile
    f32x4 a2[4];
#pragma unroll
    for (int nt = 0; nt < 4; nt++) a2[nt] = (f32x4){0.f, 0.f, 0.f, 0.f};
#pragma unroll
    for (int kc = 0; kc < 2; kc++) {
#pragma unroll
        for (int nt = 0; nt < 4; nt++) {
            const unsigned* bp = Hs + (kc * 16 + quad * 4) * 65 + nt * 16 + nl;
            bf16x8 bh; frag_kp(bp, bh);
            a2[nt] = MFMA(e2h[kc], bh, a2[nt]);
            a2[nt] = MFMA(e2l[kc], bh, a2[nt]);
        }
    }
#pragma unroll
    for (int reg = 0; reg < 4; reg++) {
        const int f = 16 * w + quad * 4 + reg;
        const float bv = e2b[f];
#pragma unroll
        for (int nt = 0; nt < 4; nt++)
            h0[((size_t)(b * 64 + f) << 12) + row * 64 + nt * 16 + nl] =
                bf16h(fmaxf(a2[nt][reg] + bv, 0.f));
    }
}

// ---- GNN layer: bf16 in, FULL-depth staging, k-paired LDS, 1 MFMA/tile ----
template <int K, bool MEAN>
__global__ __launch_bounds__(256, 4) void gnn_kernel(
    const ushort* __restrict__ hin, const ushort* __restrict__ wf,
    const float* __restrict__ bias, ushort* __restrict__ hout,
    float* __restrict__ gpart)
{
    constexpr int NQ = K / 32;            // quarters of 32 planes (= one kc each)
    __shared__ unsigned As[2][16 * 65];   // k-paired bf16, dbuf (8.3 KB)
    const int tid = threadIdx.x;
    // XCD-contiguous remap: consecutive rows on the same XCD (R7: FETCH 49->18MB)
    const int bid = ((blockIdx.x & 7) << 7) | (blockIdx.x >> 3);
    const int b = bid >> 6, row = bid & 63;
    const int lane = tid & 63, w = tid >> 6, quad = lane >> 4, nl = lane & 15;
    const int kp8 = tid >> 3, nq8 = tid & 7;   // plane 0-31, 8-node group
    const ushort* hb = hin + (size_t)b * K * 4096;
    const int rowu = (row > 0) ? row - 1 : row;
    const int rowd = (row < 63) ? row + 1 : row;
    const float su = (row > 0) ? 1.f : 0.f;
    const float sd = (row < 63) ? 1.f : 0.f;
    float inv8[8];
#pragma unroll
    for (int i = 0; i < 8; i++) {
        const int n = nq8 * 8 + i;
        const int deg = (row > 0) + (row < 63) + (n > 0) + (n < 63);
        inv8[i] = 1.f / ((float)deg + 1e-6f);
    }

    const ushort* wfl = wf + lane * 8;
    f32x4 acc[4][2];
#pragma unroll
    for (int nt = 0; nt < 4; nt++) {
        acc[nt][0] = (f32x4){0.f, 0.f, 0.f, 0.f};
        acc[nt][1] = (f32x4){0.f, 0.f, 0.f, 0.f};
    }

    float4 S[3 * NQ];     // FULL depth: every quarter staged (12 VGPR each)
    bf16x8 V[2];          // current quarter's weights [ftl], HI plane only

    auto sload = [&](int q) {             // one quarter = 32 planes, 3 loads
        const int kg = q * 32 + kp8;
        const ushort* pk = hb + ((size_t)kg << 12) + nq8 * 8;
        S[q * 3 + 0] = *(const float4*)(pk + row * 64);
        S[q * 3 + 1] = *(const float4*)(pk + rowu * 64);
        S[q * 3 + 2] = *(const float4*)(pk + rowd * 64);
    };
    auto wload = [&](int q) {
#pragma unroll
        for (int ftl = 0; ftl < 2; ftl++)
            V[ftl] = *(const bf16x8*)(wfl + ((q * 8 + 2 * w + ftl) * 2) * 512);
    };
    // stage: bf16 aggregate, K-PAIRED: dword (kp8>>1)*65+node holds
    // {k even (lo16), k odd (hi16)}; this thread fills the (kp8&1) half
    // via ds_write_b16 (pair partner lane fills the other -> 2-way, free)
    auto stage = [&](unsigned* Ab, int q) {
        const float4 c4 = S[q * 3 + 0];
        const float4 u4 = S[q * 3 + 1];
        const float4 d4 = S[q * 3 + 2];
        const unsigned cw[4] = {__float_as_uint(c4.x), __float_as_uint(c4.y),
                                __float_as_uint(c4.z), __float_as_uint(c4.w)};
        const unsigned uw[4] = {__float_as_uint(u4.x), __float_as_uint(u4.y),
                                __float_as_uint(u4.z), __float_as_uint(u4.w)};
        const unsigned dw[4] = {__float_as_uint(d4.x), __float_as_uint(d4.y),
                                __float_as_uint(d4.z), __float_as_uint(d4.w)};
        const unsigned pw = __shfl_up(cw[3], 1);    // prev lane, nodes {.,7}
        const unsigned nx = __shfl_down(cw[0], 1);  // next lane, nodes {0,.}
        ushort* aps = (ushort*)(Ab + (kp8 >> 1) * 65 + nq8 * 8) + (kp8 & 1);
        float cl = (nq8 > 0) ? bfhi(pw) : 0.f;      // left of node 0
#pragma unroll
        for (int j = 0; j < 4; j++) {
            const float ce = bflo(cw[j]), co = bfhi(cw[j]);   // nodes 2j, 2j+1
            const float ue = bflo(uw[j]), uo = bfhi(uw[j]);
            const float de = bflo(dw[j]), dd = bfhi(dw[j]);
            const float ro = (j < 3) ? bflo(cw[j + 1])
                                     : ((nq8 < 7) ? bflo(nx) : 0.f);
            aps[4 * j]     = bf16h((su * ue + sd * de + cl + co) * inv8[2 * j]);
            aps[4 * j + 2] = bf16h((su * uo + sd * dd + ce + ro) * inv8[2 * j + 1]);
            cl = co;                                 // left of next even
        }
    };
    auto consume = [&](const unsigned* Ab) {
#pragma unroll
        for (int nt = 0; nt < 4; nt++) {
            const unsigned* bp = Ab + (quad * 4) * 65 + nt * 16 + nl;
            bf16x8 bh; frag_kp(bp, bh);
            acc[nt][0] = MFMA(V[0], bh, acc[nt][0]);
            acc[nt][1] = MFMA(V[1], bh, acc[nt][1]);
        }
    };

    // prologue: issue ALL h loads for the layer; only then wait on set 0
    wload(0);
#pragma unroll
    for (int qq = 0; qq < NQ; qq++) sload(qq);
    stage(As[0], 0);           // waits set0; sets 1..NQ-1 stay in flight
    block_sync_lgkm();

#pragma unroll
    for (int q = 0; q < NQ; q++) {
        consume(As[q & 1]);                        // no drain
        if (q + 1 < NQ) {
            wload(q + 1);
            stage(As[(q + 1) & 1], q + 1);         // loads issued in prologue
            block_sync_lgkm();                     // globals stay in flight
        }
    }

    // ---- epilogue: + rowsum*bias, relu ----
    if (!MEAN) {
#pragma unroll
        for (int ftl = 0; ftl < 2; ftl++) {
            const int fb = 32 * w + 16 * ftl + quad * 4;
            const float b0 = bias[fb], b1 = bias[fb + 1], b2 = bias[fb + 2], b3 = bias[fb + 3];
#pragma unroll
            for (int nt = 0; nt < 4; nt++) {
                const int n = 16 * nt + nl;
                const int deg = (row > 0) + (row < 63) + (n > 0) + (n < 63);
                const float rs = (float)deg / ((float)deg + 1e-6f);
                ushort* op = hout + ((size_t)(b * 128 + fb) << 12) + row * 64 + n;
                op[0]        = bf16h(fmaxf(acc[nt][ftl][0] + rs * b0, 0.f));
                op[1u << 12] = bf16h(fmaxf(acc[nt][ftl][1] + rs * b1, 0.f));
                op[2u << 12] = bf16h(fmaxf(acc[nt][ftl][2] + rs * b2, 0.f));
                op[3u << 12] = bf16h(fmaxf(acc[nt][ftl][3] + rs * b3, 0.f));
            }
        }
    } else {
        // per-block row partial of the node-mean -> gpart[bid][f], NON-atomic
        // (each feature written exactly once per block; no contention, no
        // ordering needed -- the dispatch boundary publishes it to readout)
#pragma unroll
        for (int ftl = 0; ftl < 2; ftl++) {
            const int fb = 32 * w + 16 * ftl + quad * 4;
#pragma unroll
            for (int reg = 0; reg < 4; reg++) {
                const float bv = bias[fb + reg];
                float v = 0.f;
#pragma unroll
                for (int nt = 0; nt < 4; nt++) {
                    const int n = 16 * nt + nl;
                    const int deg = (row > 0) + (row < 63) + (n > 0) + (n < 63);
                    const float rs = (float)deg / ((float)deg + 1e-6f);
                    v += fmaxf(acc[nt][ftl][reg] + rs * bv, 0.f);
                }
                v += __shfl_xor(v, 1); v += __shfl_xor(v, 2);
                v += __shfl_xor(v, 4); v += __shfl_xor(v, 8);
                if (nl == 0)
                    gpart[(size_t)bid * 128 + fb + reg] = v * (1.f / 4096.f);
            }
        }
    }
}

// ---- readout: per-batch block; reduce 64 row-partials, then 2-layer MLP ----
__global__ __launch_bounds__(256) void readout_kernel(
    const float* __restrict__ gpart, const float* __restrict__ r1w,
    const float* __restrict__ r1b, const float* __restrict__ r2w,
    const float* __restrict__ r2b, float* __restrict__ out)
{
    __shared__ float gs[128];
    __shared__ float g2[256];
    const int b = blockIdx.x, tid = threadIdx.x;
    if (tid < 128) {
        const float* gp = gpart + (size_t)b * 64 * 128 + tid;
        float s = 0.f;
#pragma unroll 8
        for (int r = 0; r < 64; r++) s += gp[r * 128];   // coalesced per r
        gs[tid] = s;
    }
    __syncthreads();
    float a = r1b[tid];
#pragma unroll 16
    for (int k = 0; k < 128; k++) a = fmaf(gs[k], r1w[k * 256 + tid], a);
    g2[tid] = fmaxf(a, 0.f);
    __syncthreads();
    float a2 = r2b[tid];
#pragma unroll 16
    for (int k = 0; k < 256; k++) a2 = fmaf(g2[k], r2w[k * 256 + tid], a2);
    out[b * 256 + tid] = fmaxf(a2, 0.f);
}

extern "C" void kernel_launch(void* const* d_in, const int* in_sizes, int n_in,
                              void* d_out, int out_size, void* d_ws, size_t ws_size,
                              hipStream_t stream)
{
    const float* obs = (const float*)d_in[0];
    const float* e1w = (const float*)d_in[1];
    const float* e1b = (const float*)d_in[2];
    const float* e2w = (const float*)d_in[3];
    const float* e2b = (const float*)d_in[4];
    const float* g1w = (const float*)d_in[5];
    const float* g1b = (const float*)d_in[6];
    const float* g2w = (const float*)d_in[7];
    const float* g2b = (const float*)d_in[8];
    const float* g3w = (const float*)d_in[9];
    const float* g3b = (const float*)d_in[10];
    const float* r1w = (const float*)d_in[11];
    const float* r1b = (const float*)d_in[12];
    const float* r2w = (const float*)d_in[13];
    const float* r2b = (const float*)d_in[14];
    float* out = (float*)d_out;

    ushort* h0 = (ushort*)d_ws;                                   // 8 MB
    ushort* h1 = (ushort*)((char*)d_ws + (16u << 20));            // 16 MB
    ushort* h2 = (ushort*)((char*)d_ws + (48u << 20));            // 16 MB
    ushort* wfb = (ushort*)((char*)d_ws + (80u << 20) + 8192u);   // 184 KB
    float* gpart = (float*)((char*)d_ws + (80u << 20) + 8192u + 196608u); // 512 KB

    hipLaunchKernelGGL(prep_embed_kernel, dim3(1024), dim3(256), 0, stream,
                       obs, e1w, e1b, e2w, e2b, g1w, g2w, g3w, wfb, h0);
    hipLaunchKernelGGL((gnn_kernel<64, false>), dim3(1024), dim3(256), 0, stream,
                       h0, wfb + 12288, g1b, h1, nullptr);
    hipLaunchKernelGGL((gnn_kernel<128, false>), dim3(1024), dim3(256), 0, stream,
                       h1, wfb + 28672, g2b, h2, nullptr);
    hipLaunchKernelGGL((gnn_kernel<128, true>), dim3(1024), dim3(256), 0, stream,
                       h2, wfb + 61440, g3b, nullptr, gpart);
    hipLaunchKernelGGL(readout_kernel, dim3(16), dim3(256), 0, stream,
                       gpart, r1w, r1b, r2w, r2b, out);
}

// Round 14
// 135.591 us; speedup vs baseline: 1.0102x; 1.0102x over previous
//
#include <hip/hip_runtime.h>

// R31 = R30 (136.3-137.0us band) with prep L1 switched to BF16 OBS (the
// issue-cut lever's final site): obs staged as k-paired bf16 (bf16h, half
// the convert ops), L1 frag = frag_kp (4 ds_read, zero repack, was
// frag_packed 8+repack), L1 3->2 MFMAs (e1 weights keep hi+lo), Xs
// 2080->1040 dwords. One new rounding class (input, rel 2^-9): predicted
// absmax ~2e-3 vs 4.375e-3 threshold. R30 post-mortem: gnn MFMA halving =
// perf-neutral + bit-identical absmax -> MFMA pipe off critical path; gnn
// kept in R30 form (simpler, -8 VGPR).
// Ledger: traffic cuts pay (R21 -10), contention removal pays (R26 -3),
// issue cuts pay (R27 -3.4, R28 -2.7, R29 -3.5) then saturate (R30 0);
// falsified: gnn-fusion (R18), prep phases (R20), depth>2 (R22), WG ramp
// (R23), store coalescing (R24), fence fusion (R25: agent-release ->
// buffer_wbl2 storm; NEVER fence in wide kernels). Fill ~44us = harness
// memset of 256MB ws, not ours. If R31 is neutral, the controllable
// pipeline is at its stage-VALU/latency/boundary floor.
//
// Intermediates bf16 FEATURE-MAJOR h[b][f][n], n = 64x64 grid.
// GNN layer exact rewrite: h' = relu( agg(h) @ W + rowsum*b ).
// gnn: bf16 agg x bf16 weight, 1 MFMA per (tile,ftl).  prep L1: bf16 obs x
// hi/lo weight, 2 MFMAs; prep L2: bf16 act x hi/lo weight, 2 MFMAs.
//
// MFMA 16x16x32 bf16 layouts (verified m89/m120):
//   A (MxK): m = lane&15, k = quad*8 + j    B (KxN): n = lane&15, k = quad*8 + j
//   C/D: col(N) = lane&15, row(M) = quad*4 + reg

typedef __attribute__((ext_vector_type(8))) short bf16x8;
typedef __attribute__((ext_vector_type(4))) float f32x4;
#define MFMA(a, b, c) __builtin_amdgcn_mfma_f32_16x16x32_bf16(a, b, c, 0, 0, 0)

// barrier with LDS visibility but WITHOUT draining global loads:
// s_waitcnt imm 0xC07F = vmcnt(63) expcnt(7) lgkmcnt(0)
__device__ inline void block_sync_lgkm() {
    asm volatile("" ::: "memory");
    __builtin_amdgcn_s_waitcnt(0xC07F);
    __builtin_amdgcn_s_barrier();
    asm volatile("" ::: "memory");
}

__device__ inline ushort bf16h(float x) {
    unsigned u = __float_as_uint(x);
    return (ushort)((u + 0x7fffu + ((u >> 16) & 1u)) >> 16);
}
__device__ inline void split_bf16(float x, ushort& hi, ushort& lo) {
    hi = bf16h(x);
    lo = bf16h(x - __uint_as_float(((unsigned)hi) << 16));
}
// bf16 pair in a u32: even elem = low ushort, odd elem = high ushort
__device__ inline float bflo(unsigned w) { return __uint_as_float(w << 16); }
__device__ inline float bfhi(unsigned w) { return __uint_as_float(w & 0xFFFF0000u); }
// 4 k-paired u32 (stride 65) -> bf16x8 fragment, zero repack
__device__ inline void frag_kp(const unsigned* bp, bf16x8& bh) {
    union { bf16x8 v; unsigned d[4]; } H;
    H.d[0] = bp[0]; H.d[1] = bp[65]; H.d[2] = bp[130]; H.d[3] = bp[195];
    bh = H.v;
}

// ---- launch 1: embed (1024 blocks); g-weight prep folded into first 20 ----
// g-frag unit (kc,t) = 2 planes x 512 ushorts; per layer unit idx = kc*8 + t.
// wfb ushort offsets: g1@12288 (16 units), g2@28672 (32), g3@61440 (32).
__global__ __launch_bounds__(256, 4) void prep_embed_kernel(
    const float* __restrict__ obs,
    const float* __restrict__ e1w, const float* __restrict__ e1b,
    const float* __restrict__ e2w, const float* __restrict__ e2b,
    const float* __restrict__ g1w, const float* __restrict__ g2w,
    const float* __restrict__ g3w, ushort* __restrict__ wf,
    ushort* __restrict__ h0)
{
    const int blk = blockIdx.x, tid = threadIdx.x;

    // ---- aux: g-weight prep (blk<20, 4 units/block).
    // Outputs consumed only by LATER launches -> no intra-kernel ordering.
    if (blk < 20) {
        const int u = blk * 4 + (tid >> 6);
        const int l = tid & 63;
        const float* src; int K, kc, t; ushort* dst;
        if (u < 16)      { src = g1w; K = 64;  kc = u >> 3;        t = u & 7; dst = wf + 12288; }
        else if (u < 48) { src = g2w; K = 128; kc = (u - 16) >> 3; t = (u - 16) & 7; dst = wf + 28672; }
        else             { src = g3w; K = 128; kc = (u - 48) >> 3; t = (u - 48) & 7; dst = wf + 61440; }
        ushort* uh = dst + ((kc * 8 + t) * 2 + 0) * 512 + l * 8;
        ushort* ul = dst + ((kc * 8 + t) * 2 + 1) * 512 + l * 8;
        const int fw = t * 16 + (l & 15);
        const int kb = kc * 32 + ((l >> 4) << 3);
#pragma unroll
        for (int j = 0; j < 8; j++) {
            const int k = kb + j;
            const float wv = (k < K) ? src[k * 128 + fw] : 0.f;
            ushort hi, lo; split_bf16(wv, hi, lo);
            uh[j] = hi; ul[j] = lo;
        }
    }

    // ---- embed: block = (b, row) = 64 nodes, fused 2-layer MLP via MFMA ----
    __shared__ unsigned lds[3120];         // Xs = lds[0..1040), Hs = lds+1040
                                           // both k-paired bf16 (stride 65)
    // XCD remap ALIGNED with gnn readers: h0 rows land on the XCD that reads them
    const int ebid = ((blk & 7) << 7) | (blk >> 3);
    const int b = ebid >> 6, row = ebid & 63;
    const int lane = tid & 63, w = tid >> 6, quad = lane >> 4, nl = lane & 15;
    const int cp = tid >> 4, nq = tid & 15;

    // obs load issued early (used in phase X)
    const float4 x4 = *(const float4*)(obs + ((size_t)(b * 16 + cp) << 12) + row * 64 + nq * 4);

    // weight fragments DIRECT from global (e1w 4KB + e2w 16KB, L1-resident
    // after the first block on each CU; 64B-per-quad coalesced segments)
    float e1f[8], e2f[16];
    {
        const int f = 16 * w + nl;
#pragma unroll
        for (int j = 0; j < 8; j++) {
            const int k = quad * 8 + j;
            e1f[j] = (k < 16) ? e1w[k * 64 + f] : 0.f;
        }
#pragma unroll
        for (int kc = 0; kc < 2; kc++)
#pragma unroll
            for (int j = 0; j < 8; j++)
                e2f[kc * 8 + j] = e2w[(kc * 32 + quad * 8 + j) * 64 + f];
    }

    // phase X: stage obs as k-paired bf16 (B-operand; ch>=16 rows zeroed)
    unsigned* Xs = lds;
    unsigned* Hs = lds + 1040;
    {
        // dword (cp>>1)*65 + node holds {ch even (lo16), ch odd (hi16)};
        // this thread fills the (cp&1) half via ds_write_b16
        ushort* xps = (ushort*)(Xs + (cp >> 1) * 65 + nq * 4) + (cp & 1);
        xps[0] = bf16h(x4.x); xps[2] = bf16h(x4.y);
        xps[4] = bf16h(x4.z); xps[6] = bf16h(x4.w);
        // zero pair-rows 8..15 (k=16..31); 2 cp values share a row (benign)
        unsigned* zp = Xs + (8 + (cp & 7)) * 65 + nq * 4;
        zp[0] = 0u; zp[1] = 0u; zp[2] = 0u; zp[3] = 0u;
    }

    // build this wave's weight fragments in registers (A-operand, M=feats);
    // VALU-only, overlaps the weight-load latency before the barrier
    bf16x8 e1h, e1l, e2h[2], e2l[2];
#pragma unroll
    for (int j = 0; j < 8; j++) {
        ushort hi, lo; split_bf16(e1f[j], hi, lo);
        e1h[j] = (short)hi; e1l[j] = (short)lo;
    }
#pragma unroll
    for (int kc = 0; kc < 2; kc++)
#pragma unroll
        for (int j = 0; j < 8; j++) {
            ushort hi, lo; split_bf16(e2f[kc * 8 + j], hi, lo);
            e2h[kc][j] = (short)hi; e2l[kc][j] = (short)lo;
        }
    __syncthreads();

    // layer 1: wave w -> mid-feats 16w..16w+15 (bf16 obs, hi/lo weight);
    // activations stored bf16, K-PAIRED: dword = {fm even (lo), fm odd (hi)}
#pragma unroll
    for (int nt = 0; nt < 4; nt++) {
        const unsigned* bp = Xs + (quad * 4) * 65 + nt * 16 + nl;
        bf16x8 bh; frag_kp(bp, bh);
        f32x4 c = {0.f, 0.f, 0.f, 0.f};
        c = MFMA(e1h, bh, c); c = MFMA(e1l, bh, c);
        const int fmb = 16 * w + quad * 4;
        const unsigned d0 =
            (unsigned)bf16h(fmaxf(c[0] + e1b[fmb + 0], 0.f)) |
            ((unsigned)bf16h(fmaxf(c[1] + e1b[fmb + 1], 0.f)) << 16);
        const unsigned d1 =
            (unsigned)bf16h(fmaxf(c[2] + e1b[fmb + 2], 0.f)) |
            ((unsigned)bf16h(fmaxf(c[3] + e1b[fmb + 3], 0.f)) << 16);
        const int hr = 8 * w + quad * 2;
        Hs[hr * 65 + nt * 16 + nl] = d0;
        Hs[(hr + 1) * 65 + nt * 16 + nl] = d1;
    }
    __syncthreads();

    // layer 2: K=64 (2 kc), bf16 activations k-paired, 4 reads + 2 MFMAs/tile
    f32x4 a2[4];
#pragma unroll
    for (int nt = 0; nt < 4; nt++) a2[nt] = (f32x4){0.f, 0.f, 0.f, 0.f};
#pragma unroll
    for (int kc = 0; kc < 2; kc++) {
#pragma unroll
        for (int nt = 0; nt < 4; nt++) {
            const unsigned* bp = Hs + (kc * 16 + quad * 4) * 65 + nt * 16 + nl;
            bf16x8 bh; frag_kp(bp, bh);
            a2[nt] = MFMA(e2h[kc], bh, a2[nt]);
            a2[nt] = MFMA(e2l[kc], bh, a2[nt]);
        }
    }
#pragma unroll
    for (int reg = 0; reg < 4; reg++) {
        const int f = 16 * w + quad * 4 + reg;
        const float bv = e2b[f];
#pragma unroll
        for (int nt = 0; nt < 4; nt++)
            h0[((size_t)(b * 64 + f) << 12) + row * 64 + nt * 16 + nl] =
                bf16h(fmaxf(a2[nt][reg] + bv, 0.f));
    }
}

// ---- GNN layer: bf16 in, FULL-depth staging, k-paired LDS, 1 MFMA/tile ----
template <int K, bool MEAN>
__global__ __launch_bounds__(256, 4) void gnn_kernel(
    const ushort* __restrict__ hin, const ushort* __restrict__ wf,
    const float* __restrict__ bias, ushort* __restrict__ hout,
    float* __restrict__ gpart)
{
    constexpr int NQ = K / 32;            // quarters of 32 planes (= one kc each)
    __shared__ unsigned As[2][16 * 65];   // k-paired bf16, dbuf (8.3 KB)
    const int tid = threadIdx.x;
    // XCD-contiguous remap: consecutive rows on the same XCD (R7: FETCH 49->18MB)
    const int bid = ((blockIdx.x & 7) << 7) | (blockIdx.x >> 3);
    const int b = bid >> 6, row = bid & 63;
    const int lane = tid & 63, w = tid >> 6, quad = lane >> 4, nl = lane & 15;
    const int kp8 = tid >> 3, nq8 = tid & 7;   // plane 0-31, 8-node group
    const ushort* hb = hin + (size_t)b * K * 4096;
    const int rowu = (row > 0) ? row - 1 : row;
    const int rowd = (row < 63) ? row + 1 : row;
    const float su = (row > 0) ? 1.f : 0.f;
    const float sd = (row < 63) ? 1.f : 0.f;
    float inv8[8];
#pragma unroll
    for (int i = 0; i < 8; i++) {
        const int n = nq8 * 8 + i;
        const int deg = (row > 0) + (row < 63) + (n > 0) + (n < 63);
        inv8[i] = 1.f / ((float)deg + 1e-6f);
    }

    const ushort* wfl = wf + lane * 8;
    f32x4 acc[4][2];
#pragma unroll
    for (int nt = 0; nt < 4; nt++) {
        acc[nt][0] = (f32x4){0.f, 0.f, 0.f, 0.f};
        acc[nt][1] = (f32x4){0.f, 0.f, 0.f, 0.f};
    }

    float4 S[3 * NQ];     // FULL depth: every quarter staged (12 VGPR each)
    bf16x8 V[2];          // current quarter's weights [ftl], HI plane only

    auto sload = [&](int q) {             // one quarter = 32 planes, 3 loads
        const int kg = q * 32 + kp8;
        const ushort* pk = hb + ((size_t)kg << 12) + nq8 * 8;
        S[q * 3 + 0] = *(const float4*)(pk + row * 64);
        S[q * 3 + 1] = *(const float4*)(pk + rowu * 64);
        S[q * 3 + 2] = *(const float4*)(pk + rowd * 64);
    };
    auto wload = [&](int q) {
#pragma unroll
        for (int ftl = 0; ftl < 2; ftl++)
            V[ftl] = *(const bf16x8*)(wfl + ((q * 8 + 2 * w + ftl) * 2) * 512);
    };
    // stage: bf16 aggregate, K-PAIRED: dword (kp8>>1)*65+node holds
    // {k even (lo16), k odd (hi16)}; this thread fills the (kp8&1) half
    // via ds_write_b16 (pair partner lane fills the other -> 2-way, free)
    auto stage = [&](unsigned* Ab, int q) {
        const float4 c4 = S[q * 3 + 0];
        const float4 u4 = S[q * 3 + 1];
        const float4 d4 = S[q * 3 + 2];
        const unsigned cw[4] = {__float_as_uint(c4.x), __float_as_uint(c4.y),
                                __float_as_uint(c4.z), __float_as_uint(c4.w)};
        const unsigned uw[4] = {__float_as_uint(u4.x), __float_as_uint(u4.y),
                                __float_as_uint(u4.z), __float_as_uint(u4.w)};
        const unsigned dw[4] = {__float_as_uint(d4.x), __float_as_uint(d4.y),
                                __float_as_uint(d4.z), __float_as_uint(d4.w)};
        const unsigned pw = __shfl_up(cw[3], 1);    // prev lane, nodes {.,7}
        const unsigned nx = __shfl_down(cw[0], 1);  // next lane, nodes {0,.}
        ushort* aps = (ushort*)(Ab + (kp8 >> 1) * 65 + nq8 * 8) + (kp8 & 1);
        float cl = (nq8 > 0) ? bfhi(pw) : 0.f;      // left of node 0
#pragma unroll
        for (int j = 0; j < 4; j++) {
            const float ce = bflo(cw[j]), co = bfhi(cw[j]);   // nodes 2j, 2j+1
            const float ue = bflo(uw[j]), uo = bfhi(uw[j]);
            const float de = bflo(dw[j]), dd = bfhi(dw[j]);
            const float ro = (j < 3) ? bflo(cw[j + 1])
                                     : ((nq8 < 7) ? bflo(nx) : 0.f);
            aps[4 * j]     = bf16h((su * ue + sd * de + cl + co) * inv8[2 * j]);
            aps[4 * j + 2] = bf16h((su * uo + sd * dd + ce + ro) * inv8[2 * j + 1]);
            cl = co;                                 // left of next even
        }
    };
    auto consume = [&](const unsigned* Ab) {
#pragma unroll
        for (int nt = 0; nt < 4; nt++) {
            const unsigned* bp = Ab + (quad * 4) * 65 + nt * 16 + nl;
            bf16x8 bh; frag_kp(bp, bh);
            acc[nt][0] = MFMA(V[0], bh, acc[nt][0]);
            acc[nt][1] = MFMA(V[1], bh, acc[nt][1]);
        }
    };

    // prologue: issue ALL h loads for the layer; only then wait on set 0
    wload(0);
#pragma unroll
    for (int qq = 0; qq < NQ; qq++) sload(qq);
    stage(As[0], 0);           // waits set0; sets 1..NQ-1 stay in flight
    block_sync_lgkm();

#pragma unroll
    for (int q = 0; q < NQ; q++) {
        consume(As[q & 1]);                        // no drain
        if (q + 1 < NQ) {
            wload(q + 1);
            stage(As[(q + 1) & 1], q + 1);         // loads issued in prologue
            block_sync_lgkm();                     // globals stay in flight
        }
    }

    // ---- epilogue: + rowsum*bias, relu ----
    if (!MEAN) {
#pragma unroll
        for (int ftl = 0; ftl < 2; ftl++) {
            const int fb = 32 * w + 16 * ftl + quad * 4;
            const float b0 = bias[fb], b1 = bias[fb + 1], b2 = bias[fb + 2], b3 = bias[fb + 3];
#pragma unroll
            for (int nt = 0; nt < 4; nt++) {
                const int n = 16 * nt + nl;
                const int deg = (row > 0) + (row < 63) + (n > 0) + (n < 63);
                const float rs = (float)deg / ((float)deg + 1e-6f);
                ushort* op = hout + ((size_t)(b * 128 + fb) << 12) + row * 64 + n;
                op[0]        = bf16h(fmaxf(acc[nt][ftl][0] + rs * b0, 0.f));
                op[1u << 12] = bf16h(fmaxf(acc[nt][ftl][1] + rs * b1, 0.f));
                op[2u << 12] = bf16h(fmaxf(acc[nt][ftl][2] + rs * b2, 0.f));
                op[3u << 12] = bf16h(fmaxf(acc[nt][ftl][3] + rs * b3, 0.f));
            }
        }
    } else {
        // per-block row partial of the node-mean -> gpart[bid][f], NON-atomic
        // (each feature written exactly once per block; no contention, no
        // ordering needed -- the dispatch boundary publishes it to readout)
#pragma unroll
        for (int ftl = 0; ftl < 2; ftl++) {
            const int fb = 32 * w + 16 * ftl + quad * 4;
#pragma unroll
            for (int reg = 0; reg < 4; reg++) {
                const float bv = bias[fb + reg];
                float v = 0.f;
#pragma unroll
                for (int nt = 0; nt < 4; nt++) {
                    const int n = 16 * nt + nl;
                    const int deg = (row > 0) + (row < 63) + (n > 0) + (n < 63);
                    const float rs = (float)deg / ((float)deg + 1e-6f);
                    v += fmaxf(acc[nt][ftl][reg] + rs * bv, 0.f);
                }
                v += __shfl_xor(v, 1); v += __shfl_xor(v, 2);
                v += __shfl_xor(v, 4); v += __shfl_xor(v, 8);
                if (nl == 0)
                    gpart[(size_t)bid * 128 + fb + reg] = v * (1.f / 4096.f);
            }
        }
    }
}

// ---- readout: per-batch block; reduce 64 row-partials, then 2-layer MLP ----
__global__ __launch_bounds__(256) void readout_kernel(
    const float* __restrict__ gpart, const float* __restrict__ r1w,
    const float* __restrict__ r1b, const float* __restrict__ r2w,
    const float* __restrict__ r2b, float* __restrict__ out)
{
    __shared__ float gs[128];
    __shared__ float g2[256];
    const int b = blockIdx.x, tid = threadIdx.x;
    if (tid < 128) {
        const float* gp = gpart + (size_t)b * 64 * 128 + tid;
        float s = 0.f;
#pragma unroll 8
        for (int r = 0; r < 64; r++) s += gp[r * 128];   // coalesced per r
        gs[tid] = s;
    }
    __syncthreads();
    float a = r1b[tid];
#pragma unroll 16
    for (int k = 0; k < 128; k++) a = fmaf(gs[k], r1w[k * 256 + tid], a);
    g2[tid] = fmaxf(a, 0.f);
    __syncthreads();
    float a2 = r2b[tid];
#pragma unroll 16
    for (int k = 0; k < 256; k++) a2 = fmaf(g2[k], r2w[k * 256 + tid], a2);
    out[b * 256 + tid] = fmaxf(a2, 0.f);
}

extern "C" void kernel_launch(void* const* d_in, const int* in_sizes, int n_in,
                              void* d_out, int out_size, void* d_ws, size_t ws_size,
                              hipStream_t stream)
{
    const float* obs = (const float*)d_in[0];
    const float* e1w = (const float*)d_in[1];
    const float* e1b = (const float*)d_in[2];
    const float* e2w = (const float*)d_in[3];
    const float* e2b = (const float*)d_in[4];
    const float* g1w = (const float*)d_in[5];
    const float* g1b = (const float*)d_in[6];
    const float* g2w = (const float*)d_in[7];
    const float* g2b = (const float*)d_in[8];
    const float* g3w = (const float*)d_in[9];
    const float* g3b = (const float*)d_in[10];
    const float* r1w = (const float*)d_in[11];
    const float* r1b = (const float*)d_in[12];
    const float* r2w = (const float*)d_in[13];
    const float* r2b = (const float*)d_in[14];
    float* out = (float*)d_out;

    ushort* h0 = (ushort*)d_ws;                                   // 8 MB
    ushort* h1 = (ushort*)((char*)d_ws + (16u << 20));            // 16 MB
    ushort* h2 = (ushort*)((char*)d_ws + (48u << 20));            // 16 MB
    ushort* wfb = (ushort*)((char*)d_ws + (80u << 20) + 8192u);   // 184 KB
    float* gpart = (float*)((char*)d_ws + (80u << 20) + 8192u + 196608u); // 512 KB

    hipLaunchKernelGGL(prep_embed_kernel, dim3(1024), dim3(256), 0, stream,
                       obs, e1w, e1b, e2w, e2b, g1w, g2w, g3w, wfb, h0);
    hipLaunchKernelGGL((gnn_kernel<64, false>), dim3(1024), dim3(256), 0, stream,
                       h0, wfb + 12288, g1b, h1, nullptr);
    hipLaunchKernelGGL((gnn_kernel<128, false>), dim3(1024), dim3(256), 0, stream,
                       h1, wfb + 28672, g2b, h2, nullptr);
    hipLaunchKernelGGL((gnn_kernel<128, true>), dim3(1024), dim3(256), 0, stream,
                       h2, wfb + 61440, g3b, nullptr, gpart);
    hipLaunchKernelGGL(readout_kernel, dim3(16), dim3(256), 0, stream,
                       gpart, r1w, r1b, r2w, r2b, out);
}